// Round 1
// baseline (5285.624 us; speedup 1.0000x reference)
//
#include <hip/hip_runtime.h>

#define VN 30000
#define CN 120000
#define EPN 180000
#define ENN 180000
#define DD 128
#define BN 32

static __device__ __forceinline__ float sigm(float x){ return 1.0f/(1.0f+__expf(-x)); }

// ---------------- edge endpoints + degrees ----------------
__global__ __launch_bounds__(256) void k_edges(
    const int* __restrict__ vE, const int* __restrict__ cE,
    const int* __restrict__ pE, const int* __restrict__ nE,
    int* __restrict__ p_v, int* __restrict__ p_c,
    int* __restrict__ n_v, int* __restrict__ n_c,
    float* __restrict__ dpv, float* __restrict__ dnv,
    float* __restrict__ dpc, float* __restrict__ dnc)
{
  int i = blockIdx.x*256 + threadIdx.x;
  if (i < EPN){
    int e = pE[i]; int v = vE[e], c = cE[e];
    p_v[i] = v; p_c[i] = c;
    atomicAdd(&dpv[v], 1.0f); atomicAdd(&dpc[c], 1.0f);
  }
  if (i < ENN){
    int e = nE[i]; int v = vE[e], c = cE[e];
    n_v[i] = v; n_c[i] = c;
    atomicAdd(&dnv[v], 1.0f); atomicAdd(&dnc[c], 1.0f);
  }
}

__global__ __launch_bounds__(256) void k_recip(float* __restrict__ d, int n){
  int i = blockIdx.x*256 + threadIdx.x;
  if (i < n) d[i] = 1.0f / fmaxf(d[i], 1.0f);
}

__global__ __launch_bounds__(256) void k_init(const float* __restrict__ ini, float* __restrict__ emb, int total){
  int i = blockIdx.x*256 + threadIdx.x;
  if (i < total) emb[i] = ini[i & (DD-1)] * 0.08838834764831845f; // 1/sqrt(128)
}

// ---------------- two-layer MLP: Y = relu(X@W1+b1)@W2+b2 ----------------
// 32 rows/block, 256 threads, thread = 4 rows x 4 cols; weights streamed from L2.
__global__ __launch_bounds__(256) void k_mlp2(
    const float* __restrict__ X,
    const float* __restrict__ W1, const float* __restrict__ b1,
    const float* __restrict__ W2, const float* __restrict__ b2,
    float* __restrict__ Y, int M)
{
  __shared__ float sX[32][DD];
  __shared__ float sH[32][DD];
  int t = threadIdx.x;
  int row0 = blockIdx.x * 32;
  for (int i = t; i < 32*DD/4; i += 256){
    int r = i >> 5; int c = (i*4) & (DD-1);
    int gr = row0 + r;
    float4 v = (gr < M) ? *(const float4*)&X[(size_t)gr*DD + c] : make_float4(0,0,0,0);
    *(float4*)&sX[r][c] = v;
  }
  __syncthreads();
  int c0 = (t & 31) * 4;
  int r0 = (t >> 5) * 4;
  float acc[4][4];
  #pragma unroll
  for (int i=0;i<4;i++){ acc[i][0]=0.f; acc[i][1]=0.f; acc[i][2]=0.f; acc[i][3]=0.f; }
  #pragma unroll 8
  for (int k=0;k<DD;k++){
    float4 w = *(const float4*)&W1[(size_t)k*DD + c0];
    #pragma unroll
    for (int i=0;i<4;i++){
      float x = sX[r0+i][k];
      acc[i][0]=fmaf(x,w.x,acc[i][0]); acc[i][1]=fmaf(x,w.y,acc[i][1]);
      acc[i][2]=fmaf(x,w.z,acc[i][2]); acc[i][3]=fmaf(x,w.w,acc[i][3]);
    }
  }
  float4 bb = *(const float4*)&b1[c0];
  #pragma unroll
  for (int i=0;i<4;i++){
    float4 hv;
    hv.x = fmaxf(acc[i][0]+bb.x, 0.f); hv.y = fmaxf(acc[i][1]+bb.y, 0.f);
    hv.z = fmaxf(acc[i][2]+bb.z, 0.f); hv.w = fmaxf(acc[i][3]+bb.w, 0.f);
    *(float4*)&sH[r0+i][c0] = hv;
  }
  __syncthreads();
  #pragma unroll
  for (int i=0;i<4;i++){ acc[i][0]=0.f; acc[i][1]=0.f; acc[i][2]=0.f; acc[i][3]=0.f; }
  #pragma unroll 8
  for (int k=0;k<DD;k++){
    float4 w = *(const float4*)&W2[(size_t)k*DD + c0];
    #pragma unroll
    for (int i=0;i<4;i++){
      float x = sH[r0+i][k];
      acc[i][0]=fmaf(x,w.x,acc[i][0]); acc[i][1]=fmaf(x,w.y,acc[i][1]);
      acc[i][2]=fmaf(x,w.z,acc[i][2]); acc[i][3]=fmaf(x,w.w,acc[i][3]);
    }
  }
  float4 b2v = *(const float4*)&b2[c0];
  #pragma unroll
  for (int i=0;i<4;i++){
    int gr = row0 + r0 + i;
    if (gr < M){
      float4 o;
      o.x = acc[i][0]+b2v.x; o.y = acc[i][1]+b2v.y;
      o.z = acc[i][2]+b2v.z; o.w = acc[i][3]+b2v.w;
      *(float4*)&Y[(size_t)gr*DD + c0] = o;
    }
  }
}

// ---------------- scatter-add H rows into aggregation buffer ----------------
__global__ __launch_bounds__(256) void k_scatter(
    const float* __restrict__ H, const int* __restrict__ src, const int* __restrict__ dst,
    float* __restrict__ Xg, int nE, int colOff)
{
  int idx = blockIdx.x*256 + threadIdx.x;
  int e = idx >> 6;
  if (e >= nE) return;
  int c2 = (idx & 63) * 2;
  int s = src[e], d = dst[e];
  float2 v = *(const float2*)&H[(size_t)s*DD + c2];
  float* p = &Xg[(size_t)d*(2*DD) + colOff + c2];
  atomicAdd(p,   v.x);
  atomicAdd(p+1, v.y);
}

// ---------------- fused GRU cell (in-place h update) ----------------
__device__ __forceinline__ void gru_gate(
    const float (*sX)[2*DD], const float (*sHs)[DD],
    const float* __restrict__ Wih, const float* __restrict__ Whh,
    const float* __restrict__ bih, const float* __restrict__ bhh,
    int g, int r0, int c0, float (&aI)[4][4], float (&aH)[4][4])
{
  #pragma unroll
  for (int i=0;i<4;i++){ aI[i][0]=0.f;aI[i][1]=0.f;aI[i][2]=0.f;aI[i][3]=0.f;
                         aH[i][0]=0.f;aH[i][1]=0.f;aH[i][2]=0.f;aH[i][3]=0.f; }
  const float* wp = Wih + g*DD + c0;
  #pragma unroll 4
  for (int k=0;k<2*DD;k++){
    float4 w = *(const float4*)(wp + (size_t)k*(3*DD));
    #pragma unroll
    for (int i=0;i<4;i++){
      float x = sX[r0+i][k];
      aI[i][0]=fmaf(x,w.x,aI[i][0]); aI[i][1]=fmaf(x,w.y,aI[i][1]);
      aI[i][2]=fmaf(x,w.z,aI[i][2]); aI[i][3]=fmaf(x,w.w,aI[i][3]);
    }
  }
  const float* hp = Whh + g*DD + c0;
  #pragma unroll 4
  for (int k=0;k<DD;k++){
    float4 w = *(const float4*)(hp + (size_t)k*(3*DD));
    #pragma unroll
    for (int i=0;i<4;i++){
      float x = sHs[r0+i][k];
      aH[i][0]=fmaf(x,w.x,aH[i][0]); aH[i][1]=fmaf(x,w.y,aH[i][1]);
      aH[i][2]=fmaf(x,w.z,aH[i][2]); aH[i][3]=fmaf(x,w.w,aH[i][3]);
    }
  }
  float4 bi = *(const float4*)&bih[g*DD+c0];
  float4 bh = *(const float4*)&bhh[g*DD+c0];
  #pragma unroll
  for (int i=0;i<4;i++){
    aI[i][0]+=bi.x; aI[i][1]+=bi.y; aI[i][2]+=bi.z; aI[i][3]+=bi.w;
    aH[i][0]+=bh.x; aH[i][1]+=bh.y; aH[i][2]+=bh.z; aH[i][3]+=bh.w;
  }
}

__global__ __launch_bounds__(256) void k_gru(
    float* __restrict__ h, const float* __restrict__ Xg,
    const float* __restrict__ rp, const float* __restrict__ rn,
    const float* __restrict__ Wih, const float* __restrict__ Whh,
    const float* __restrict__ bih, const float* __restrict__ bhh, int M)
{
  __shared__ float sX[32][2*DD];
  __shared__ float sHs[32][DD];
  int t = threadIdx.x;
  int row0 = blockIdx.x * 32;
  for (int i = t; i < 32*2*DD/4; i += 256){
    int r = i >> 6; int c = (i*4) & (2*DD-1);
    int gr = row0 + r;
    float4 v = make_float4(0,0,0,0);
    if (gr < M){
      v = *(const float4*)&Xg[(size_t)gr*(2*DD) + c];
      float s = (c < DD) ? rp[gr] : rn[gr];
      v.x*=s; v.y*=s; v.z*=s; v.w*=s;
    }
    *(float4*)&sX[r][c] = v;
  }
  for (int i = t; i < 32*DD/4; i += 256){
    int r = i >> 5; int c = (i*4) & (DD-1);
    int gr = row0 + r;
    float4 v = (gr < M) ? *(const float4*)&h[(size_t)gr*DD + c] : make_float4(0,0,0,0);
    *(float4*)&sHs[r][c] = v;
  }
  __syncthreads();
  int c0 = (t & 31) * 4;
  int r0 = (t >> 5) * 4;
  float aI[4][4], aH[4][4], rr[4][4], zz[4][4];
  gru_gate(sX,sHs,Wih,Whh,bih,bhh,0,r0,c0,aI,aH);
  #pragma unroll
  for (int i=0;i<4;i++){ rr[i][0]=sigm(aI[i][0]+aH[i][0]); rr[i][1]=sigm(aI[i][1]+aH[i][1]);
                         rr[i][2]=sigm(aI[i][2]+aH[i][2]); rr[i][3]=sigm(aI[i][3]+aH[i][3]); }
  gru_gate(sX,sHs,Wih,Whh,bih,bhh,1,r0,c0,aI,aH);
  #pragma unroll
  for (int i=0;i<4;i++){ zz[i][0]=sigm(aI[i][0]+aH[i][0]); zz[i][1]=sigm(aI[i][1]+aH[i][1]);
                         zz[i][2]=sigm(aI[i][2]+aH[i][2]); zz[i][3]=sigm(aI[i][3]+aH[i][3]); }
  gru_gate(sX,sHs,Wih,Whh,bih,bhh,2,r0,c0,aI,aH);
  #pragma unroll
  for (int i=0;i<4;i++){
    int gr = row0 + r0 + i;
    if (gr < M){
      float4 o;
      float n0 = tanhf(aI[i][0] + rr[i][0]*aH[i][0]);
      float n1 = tanhf(aI[i][1] + rr[i][1]*aH[i][1]);
      float n2 = tanhf(aI[i][2] + rr[i][2]*aH[i][2]);
      float n3 = tanhf(aI[i][3] + rr[i][3]*aH[i][3]);
      o.x = (1.f-zz[i][0])*n0 + zz[i][0]*sHs[r0+i][c0+0];
      o.y = (1.f-zz[i][1])*n1 + zz[i][1]*sHs[r0+i][c0+1];
      o.z = (1.f-zz[i][2])*n2 + zz[i][2]*sHs[r0+i][c0+2];
      o.w = (1.f-zz[i][3])*n3 + zz[i][3]*sHs[r0+i][c0+3];
      *(float4*)&h[(size_t)gr*DD + c0] = o;
    }
  }
}

// ---------------- per-graph mean readout ----------------
__global__ __launch_bounds__(256) void k_batchsum(
    const float* __restrict__ v_emb, const int* __restrict__ vb,
    float* __restrict__ g_sum, float* __restrict__ g_cnt)
{
  int c = threadIdx.x & (DD-1);
  int half = threadIdx.x >> 7;
  int rs = blockIdx.x*128 + half*64;
  if (rs >= VN) return;
  int re = rs + 64; if (re > VN) re = VN;
  float acc = 0.f, cnt = 0.f;
  int cur = vb[rs];
  for (int r = rs; r < re; r++){
    int b = vb[r];
    if (b != cur){
      atomicAdd(&g_sum[cur*DD + c], acc);
      if (c == 0) atomicAdd(&g_cnt[cur], cnt);
      acc = 0.f; cnt = 0.f; cur = b;
    }
    acc += v_emb[(size_t)r*DD + c];
    cnt += 1.f;
  }
  atomicAdd(&g_sum[cur*DD + c], acc);
  if (c == 0) atomicAdd(&g_cnt[cur], cnt);
}

__global__ __launch_bounds__(128) void k_readout(
    const float* __restrict__ g_sum, const float* __restrict__ g_cnt,
    const float* __restrict__ W1, const float* __restrict__ b1,
    const float* __restrict__ W2, const float* __restrict__ b2,
    float* __restrict__ out)
{
  __shared__ float sg[DD];
  __shared__ float sr[DD];
  int b = blockIdx.x, c = threadIdx.x;
  float rc = 1.0f / fmaxf(g_cnt[b], 1.0f);
  sg[c] = g_sum[b*DD + c] * rc;
  __syncthreads();
  float a = b1[c];
  for (int k=0;k<DD;k++) a = fmaf(sg[k], W1[(size_t)k*DD + c], a);
  a = fmaxf(a, 0.f);
  sr[c] = a * W2[c];
  __syncthreads();
  for (int s=64; s>0; s>>=1){
    if (c < s) sr[c] += sr[c+s];
    __syncthreads();
  }
  if (c == 0) out[b] = sigm(sr[0] + b2[0]);
}

// ---------------- orchestration ----------------
extern "C" void kernel_launch(void* const* d_in, const int* in_sizes, int n_in,
                              void* d_out, int out_size, void* d_ws, size_t ws_size,
                              hipStream_t stream)
{
  const int* vE = (const int*)d_in[0];
  const int* cE = (const int*)d_in[1];
  const int* pE = (const int*)d_in[2];
  const int* nE = (const int*)d_in[3];
  const int* vb = (const int*)d_in[4];
  const float* v_init = (const float*)d_in[5];
  const float* c_init = (const float*)d_in[6];
  const float* mW1[4]; const float* mb1[4]; const float* mW2[4]; const float* mb2[4];
  for (int m=0;m<4;m++){
    mW1[m] = (const float*)d_in[7 + m*4 + 0];
    mb1[m] = (const float*)d_in[7 + m*4 + 1];
    mW2[m] = (const float*)d_in[7 + m*4 + 2];
    mb2[m] = (const float*)d_in[7 + m*4 + 3];
  }
  // 0: p_v2c, 1: n_v2c, 2: p_c2v, 3: n_c2v
  const float* gc_Wih = (const float*)d_in[23];
  const float* gc_Whh = (const float*)d_in[24];
  const float* gc_bih = (const float*)d_in[25];
  const float* gc_bhh = (const float*)d_in[26];
  const float* gv_Wih = (const float*)d_in[27];
  const float* gv_Whh = (const float*)d_in[28];
  const float* gv_bih = (const float*)d_in[29];
  const float* gv_bhh = (const float*)d_in[30];
  const float* ro_W1 = (const float*)d_in[31];
  const float* ro_b1 = (const float*)d_in[32];
  const float* ro_W2 = (const float*)d_in[33];
  const float* ro_b2 = (const float*)d_in[34];
  float* out = (float*)d_out;

  char* base = (char*)d_ws;
  size_t off = 0;
  auto alloc = [&](size_t n)->void*{ void* p = base + off; off += (n + 255) & ~(size_t)255; return p; };
  int*   p_v   = (int*)  alloc((size_t)EPN*4);
  int*   p_c   = (int*)  alloc((size_t)EPN*4);
  int*   n_v   = (int*)  alloc((size_t)ENN*4);
  int*   n_c   = (int*)  alloc((size_t)ENN*4);
  float* dpv   = (float*)alloc((size_t)VN*4);
  float* dnv   = (float*)alloc((size_t)VN*4);
  float* dpc   = (float*)alloc((size_t)CN*4);
  float* dnc   = (float*)alloc((size_t)CN*4);
  float* v_emb = (float*)alloc((size_t)VN*DD*4);
  float* c_emb = (float*)alloc((size_t)CN*DD*4);
  float* Hbuf  = (float*)alloc((size_t)CN*DD*4);
  float* Xg    = (float*)alloc((size_t)CN*2*DD*4);
  float* g_sum = (float*)alloc((size_t)BN*DD*4);
  float* g_cnt = (float*)alloc((size_t)BN*4);
  (void)ws_size; (void)in_sizes; (void)n_in; (void)out_size;

  hipMemsetAsync(dpv, 0, (size_t)VN*4, stream);
  hipMemsetAsync(dnv, 0, (size_t)VN*4, stream);
  hipMemsetAsync(dpc, 0, (size_t)CN*4, stream);
  hipMemsetAsync(dnc, 0, (size_t)CN*4, stream);

  k_edges<<<(EPN+255)/256, 256, 0, stream>>>(vE, cE, pE, nE, p_v, p_c, n_v, n_c, dpv, dnv, dpc, dnc);
  k_recip<<<(VN+255)/256, 256, 0, stream>>>(dpv, VN);
  k_recip<<<(VN+255)/256, 256, 0, stream>>>(dnv, VN);
  k_recip<<<(CN+255)/256, 256, 0, stream>>>(dpc, CN);
  k_recip<<<(CN+255)/256, 256, 0, stream>>>(dnc, CN);
  k_init<<<((size_t)VN*DD+255)/256, 256, 0, stream>>>(v_init, v_emb, VN*DD);
  k_init<<<((size_t)CN*DD+255)/256, 256, 0, stream>>>(c_init, c_emb, CN*DD);

  int mlpV = (VN+31)/32, mlpC = (CN+31)/32;
  int scP = (EPN*64+255)/256, scN = (ENN*64+255)/256;

  for (int it=0; it<3; ++it){
    // ---- v -> c ----
    hipMemsetAsync(Xg, 0, (size_t)CN*2*DD*4, stream);
    k_mlp2<<<mlpV, 256, 0, stream>>>(v_emb, mW1[0], mb1[0], mW2[0], mb2[0], Hbuf, VN);
    k_scatter<<<scP, 256, 0, stream>>>(Hbuf, p_v, p_c, Xg, EPN, 0);
    k_mlp2<<<mlpV, 256, 0, stream>>>(v_emb, mW1[1], mb1[1], mW2[1], mb2[1], Hbuf, VN);
    k_scatter<<<scN, 256, 0, stream>>>(Hbuf, n_v, n_c, Xg, ENN, DD);
    k_gru<<<mlpC, 256, 0, stream>>>(c_emb, Xg, dpc, dnc, gc_Wih, gc_Whh, gc_bih, gc_bhh, CN);
    // ---- c -> v ----
    hipMemsetAsync(Xg, 0, (size_t)VN*2*DD*4, stream);
    k_mlp2<<<mlpC, 256, 0, stream>>>(c_emb, mW1[2], mb1[2], mW2[2], mb2[2], Hbuf, CN);
    k_scatter<<<scP, 256, 0, stream>>>(Hbuf, p_c, p_v, Xg, EPN, 0);
    k_mlp2<<<mlpC, 256, 0, stream>>>(c_emb, mW1[3], mb1[3], mW2[3], mb2[3], Hbuf, CN);
    k_scatter<<<scN, 256, 0, stream>>>(Hbuf, n_c, n_v, Xg, ENN, DD);
    k_gru<<<mlpV, 256, 0, stream>>>(v_emb, Xg, dpv, dnv, gv_Wih, gv_Whh, gv_bih, gv_bhh, VN);
  }

  hipMemsetAsync(g_sum, 0, (size_t)BN*DD*4, stream);
  hipMemsetAsync(g_cnt, 0, (size_t)BN*4, stream);
  k_batchsum<<<(VN+127)/128, 256, 0, stream>>>(v_emb, vb, g_sum, g_cnt);
  k_readout<<<BN, 128, 0, stream>>>(g_sum, g_cnt, ro_W1, ro_b1, ro_W2, ro_b2, out);
}

// Round 2
// 1257.853 us; speedup vs baseline: 4.2021x; 4.2021x over previous
//
#include <hip/hip_runtime.h>

#define VN 30000
#define CN 120000
#define EPN 180000
#define ENN 180000
#define DD 128
#define BN 32
#define SCN (2*VN + 2*CN)          // 300000 concatenated degree rows: PV | NV | PC | NC
#define SC_NB ((SCN + 1023) / 1024) // 293 scan blocks

using bf16x8 = __attribute__((ext_vector_type(8))) short;
using f32x4  = __attribute__((ext_vector_type(4))) float;

static __device__ __forceinline__ float sigm(float x){ return 1.0f/(1.0f+__expf(-x)); }
static __device__ __forceinline__ unsigned short f2b(float f){
  unsigned int u = __float_as_uint(f);
  unsigned int r = u + 0x7fffu + ((u>>16)&1u);
  return (unsigned short)(r>>16);
}
static __device__ __forceinline__ float b2f(unsigned short s){
  return __uint_as_float(((unsigned int)s)<<16);
}

// ---------------- edge endpoints + integer degree counts ----------------
__global__ __launch_bounds__(256) void k_edges(
    const int* __restrict__ vE, const int* __restrict__ cE,
    const int* __restrict__ pE, const int* __restrict__ nE,
    int* __restrict__ p_v, int* __restrict__ p_c,
    int* __restrict__ n_v, int* __restrict__ n_c,
    int* __restrict__ cnt)
{
  int i = blockIdx.x*256 + threadIdx.x;
  if (i < EPN){
    int e = pE[i]; int v = vE[e], c = cE[e];
    p_v[i] = v; p_c[i] = c;
    atomicAdd(&cnt[v], 1); atomicAdd(&cnt[2*VN + c], 1);
  }
  if (i < ENN){
    int e = nE[i]; int v = vE[e], c = cE[e];
    n_v[i] = v; n_c[i] = c;
    atomicAdd(&cnt[VN + v], 1); atomicAdd(&cnt[2*VN + CN + c], 1);
  }
}

// ---------------- 3-phase exclusive scan over cnt[SCN] ----------------
__global__ __launch_bounds__(256) void k_scan1(const int* __restrict__ cnt, int* __restrict__ part, int* __restrict__ bsum){
  __shared__ int s[256];
  int b = blockIdx.x, t = threadIdx.x;
  int base = b*1024 + t*4;
  int v0 = (base+0<SCN)?cnt[base+0]:0;
  int v1 = (base+1<SCN)?cnt[base+1]:0;
  int v2 = (base+2<SCN)?cnt[base+2]:0;
  int v3 = (base+3<SCN)?cnt[base+3]:0;
  int loc = v0+v1+v2+v3;
  s[t] = loc; __syncthreads();
  for (int off=1; off<256; off<<=1){
    int x = (t>=off)? s[t-off] : 0;
    __syncthreads();
    s[t] += x;
    __syncthreads();
  }
  int excl = s[t]-loc;
  if (t==255) bsum[b] = s[255];
  if (base  <SCN) part[base  ] = excl;
  if (base+1<SCN) part[base+1] = excl+v0;
  if (base+2<SCN) part[base+2] = excl+v0+v1;
  if (base+3<SCN) part[base+3] = excl+v0+v1+v2;
}
__global__ __launch_bounds__(512) void k_scan2(const int* __restrict__ bsum, int* __restrict__ boff, int* __restrict__ total_out){
  __shared__ int s[512];
  int t = threadIdx.x;
  int v = (t<SC_NB)? bsum[t] : 0;
  s[t]=v; __syncthreads();
  for (int off=1; off<512; off<<=1){
    int x = (t>=off)? s[t-off] : 0;
    __syncthreads();
    s[t]+=x;
    __syncthreads();
  }
  if (t<SC_NB) boff[t] = s[t]-v;
  if (t==511) total_out[0] = s[511];
}
__global__ __launch_bounds__(256) void k_scan3(int* __restrict__ part, const int* __restrict__ boff){
  int b = blockIdx.x; int base = b*1024 + threadIdx.x*4; int o = boff[b];
  #pragma unroll
  for (int i=0;i<4;i++) if (base+i < SCN) part[base+i] += o;
}

// ---------------- CSR bucket fill ----------------
__global__ __launch_bounds__(256) void k_fill(
    const int* __restrict__ p_v, const int* __restrict__ p_c,
    const int* __restrict__ n_v, const int* __restrict__ n_c,
    const int* __restrict__ starts, int* __restrict__ fill, int* __restrict__ listBuf)
{
  int i = blockIdx.x*256 + threadIdx.x;
  if (i < EPN){
    int v = p_v[i], c = p_c[i];
    int s1 = starts[v]        + atomicAdd(&fill[v], 1);          listBuf[s1] = c; // PV: per-v list of c
    int s2 = starts[2*VN + c] + atomicAdd(&fill[2*VN + c], 1);   listBuf[s2] = v; // PC: per-c list of v
  }
  if (i < ENN){
    int v = n_v[i], c = n_c[i];
    int s1 = starts[VN + v]        + atomicAdd(&fill[VN + v], 1);        listBuf[s1] = c; // NV
    int s2 = starts[2*VN + CN + c] + atomicAdd(&fill[2*VN + CN + c], 1); listBuf[s2] = v; // NC
  }
}

__global__ __launch_bounds__(256) void k_rdeg(const int* __restrict__ cnt, float* __restrict__ rdeg){
  int i = blockIdx.x*256 + threadIdx.x;
  if (i < SCN) rdeg[i] = 1.0f / (float)max(cnt[i], 1);
}

// ---------------- weight packing: W[K][N] f32 -> fragment-major bf16 ----------------
// layout: Wp[((n0*(K/32)+k0)*64 + lane)*8 + j] = bf16(W[k0*32 + (lane>>4)*8 + j][n0*16 + (lane&15)])
__global__ __launch_bounds__(256) void k_pack(const float* __restrict__ W, unsigned short* __restrict__ Wp, int K, int N){
  int o = blockIdx.x*256 + threadIdx.x;
  if (o >= K*N) return;
  int j = o & 7, l = (o>>3) & 63, frag = o >> 9;
  int K32 = K >> 5;
  int n0 = frag / K32, k0 = frag - n0*K32;
  int k = k0*32 + (l>>4)*8 + j, n = n0*16 + (l&15);
  Wp[o] = f2b(W[(size_t)k*N + n]);
}

__global__ __launch_bounds__(256) void k_init(const float* __restrict__ ini, float* __restrict__ emb, int total){
  int i = blockIdx.x*256 + threadIdx.x;
  if (i < total) emb[i] = ini[i & (DD-1)] * 0.08838834764831845f; // 1/sqrt(128)
}

// ---------------- MFMA helpers ----------------
// LDS tile [16][128] bf16, row stride 256B, 16B-block swizzle: blk ^= (row&7)
static __device__ __forceinline__ void loadA(bf16x8 a[4], const char* lds, int lane){
  int row = lane & 15, h = lane >> 4;
  #pragma unroll
  for (int k0=0;k0<4;k0++)
    a[k0] = *(const bf16x8*)&lds[row*256 + (((k0*4 + h) ^ (row & 7)) << 4)];
}

// one 128->128 layer: frags a[4] x packed W -> bf16 into outLDS (swizzled)
static __device__ __forceinline__ void layer128(const bf16x8 a[4], const unsigned short* __restrict__ Wp,
                                                const float* __restrict__ bias, char* outLDS, int lane, bool relu){
  int col0 = lane & 15, hq = lane >> 4;
  #pragma unroll
  for (int n0=0;n0<8;n0++){
    f32x4 acc = {0.f,0.f,0.f,0.f};
    #pragma unroll
    for (int k0=0;k0<4;k0++){
      bf16x8 w = *(const bf16x8*)&Wp[((n0*4 + k0)*64 + lane)*8];
      acc = __builtin_amdgcn_mfma_f32_16x16x32_bf16(a[k0], w, acc, 0, 0, 0);
    }
    int col = n0*16 + col0;
    float b = bias[col];
    #pragma unroll
    for (int r=0;r<4;r++){
      float v = acc[r] + b;
      if (relu) v = fmaxf(v, 0.f);
      int row = hq*4 + r;
      *(unsigned short*)&outLDS[row*256 + (((col>>3) ^ (row&7)) << 4) + (col&7)*2] = f2b(v);
    }
  }
}

// ---------------- dual two-layer MLP (pos & neg share X staging) ----------------
__global__ __launch_bounds__(256) void k_mlp2dual(
    const float* __restrict__ X,
    const unsigned short* __restrict__ W1p, const float* __restrict__ b1p,
    const unsigned short* __restrict__ W2p, const float* __restrict__ b2p,
    const unsigned short* __restrict__ W1n, const float* __restrict__ b1n,
    const unsigned short* __restrict__ W2n, const float* __restrict__ b2n,
    unsigned short* __restrict__ Hp, unsigned short* __restrict__ Hn, int M)
{
  __shared__ __align__(16) char smem[49152];
  int t = threadIdx.x, lane = t & 63, wid = t >> 6;
  int r0 = blockIdx.x*64 + wid*16;
  if (r0 >= M) return;
  char* sX  = smem + wid*12288;  // [16][128] bf16, 4KB
  char* sH1 = sX + 4096;
  char* sH2 = sX + 8192;
  // stage X rows (f32 -> bf16, swizzled)
  #pragma unroll
  for (int q=0;q<8;q++){
    int i = lane + q*64; int row = i>>5, fb = i&31;
    float4 v = *(const float4*)&X[(size_t)(r0+row)*DD + fb*4];
    ushort4 hv; hv.x=f2b(v.x); hv.y=f2b(v.y); hv.z=f2b(v.z); hv.w=f2b(v.w);
    *(ushort4*)&sX[row*256 + (((fb>>1) ^ (row&7)) << 4) + (fb&1)*8] = hv;
  }
  bf16x8 aX[4]; loadA(aX, sX, lane);
  layer128(aX, W1p, b1p, sH1, lane, true);
  layer128(aX, W1n, b1n, sH2, lane, true);
  bf16x8 aH[4];
  loadA(aH, sH1, lane);
  layer128(aH, W2p, b2p, sX, lane, false);   // sX free (aX in regs)
  #pragma unroll
  for (int q=0;q<4;q++){
    int i = lane + q*64; int row = i>>4, cb = i&15;
    *(uint4*)&Hp[(size_t)(r0+row)*DD + cb*8] = *(const uint4*)&sX[row*256 + ((cb ^ (row&7)) << 4)];
  }
  loadA(aH, sH2, lane);
  layer128(aH, W2n, b2n, sH1, lane, false);
  #pragma unroll
  for (int q=0;q<4;q++){
    int i = lane + q*64; int row = i>>4, cb = i&15;
    *(uint4*)&Hn[(size_t)(r0+row)*DD + cb*8] = *(const uint4*)&sH1[row*256 + ((cb ^ (row&7)) << 4)];
  }
}

// ---------------- CSR gather-mean aggregation: 1 wave per destination ----------------
__global__ __launch_bounds__(256) void k_aggr(
    const unsigned short* __restrict__ Hp, const unsigned short* __restrict__ Hn,
    const int* __restrict__ starts, const float* __restrict__ rdeg, const int* __restrict__ listBuf,
    unsigned short* __restrict__ Xg, int baseP, int baseN, int M)
{
  int d = blockIdx.x*4 + (threadIdx.x >> 6);
  if (d >= M) return;
  int lane = threadIdx.x & 63;
  float a0=0.f, a1=0.f;
  int s = starts[baseP + d], e = starts[baseP + d + 1];
  for (int q=s; q<e; q++){
    int src = listBuf[q];
    ushort2 u = *(const ushort2*)&Hp[(size_t)src*DD + lane*2];
    a0 += b2f(u.x); a1 += b2f(u.y);
  }
  float rp = rdeg[baseP + d];
  ushort2 o; o.x = f2b(a0*rp); o.y = f2b(a1*rp);
  *(ushort2*)&Xg[(size_t)d*(2*DD) + lane*2] = o;
  a0=0.f; a1=0.f;
  s = starts[baseN + d]; e = starts[baseN + d + 1];
  for (int q=s; q<e; q++){
    int src = listBuf[q];
    ushort2 u = *(const ushort2*)&Hn[(size_t)src*DD + lane*2];
    a0 += b2f(u.x); a1 += b2f(u.y);
  }
  float rn = rdeg[baseN + d];
  o.x = f2b(a0*rn); o.y = f2b(a1*rn);
  *(unsigned short*)&Xg[(size_t)d*(2*DD) + DD + lane*2]     = o.x;
  *(unsigned short*)&Xg[(size_t)d*(2*DD) + DD + lane*2 + 1] = o.y;
}

// ---------------- fused GRU cell, MFMA, in-place f32 h update ----------------
__global__ __launch_bounds__(256) void k_gru(
    float* __restrict__ h, const unsigned short* __restrict__ Xg,
    const unsigned short* __restrict__ Wih, const unsigned short* __restrict__ Whh,
    const float* __restrict__ bih, const float* __restrict__ bhh, int M)
{
  __shared__ __align__(16) char smem[49152];
  int t = threadIdx.x, lane = t & 63, wid = t >> 6;
  int r0 = blockIdx.x*64 + wid*16;
  if (r0 >= M) return;
  char* sXg = smem + wid*12288;   // [16][256] bf16, 8KB
  char* sh  = sXg + 8192;        // [16][128] bf16, 4KB
  // stage Xg (bf16 16B blocks, swizzled)
  #pragma unroll
  for (int q=0;q<8;q++){
    int i = lane + q*64; int row = i>>5, cb = i&31;
    *(uint4*)&sXg[row*512 + ((cb ^ (row&7)) << 4)] = *(const uint4*)&Xg[(size_t)(r0+row)*(2*DD) + cb*8];
  }
  // stage h (f32 -> bf16)
  #pragma unroll
  for (int q=0;q<8;q++){
    int i = lane + q*64; int row = i>>5, fb = i&31;
    float4 v = *(const float4*)&h[(size_t)(r0+row)*DD + fb*4];
    ushort4 u; u.x=f2b(v.x); u.y=f2b(v.y); u.z=f2b(v.z); u.w=f2b(v.w);
    *(ushort4*)&sh[row*256 + (((fb>>1) ^ (row&7)) << 4) + (fb&1)*8] = u;
  }
  bf16x8 aX[8];
  {
    int row = lane & 15, hq = lane >> 4;
    #pragma unroll
    for (int k0=0;k0<8;k0++)
      aX[k0] = *(const bf16x8*)&sXg[row*512 + (((k0*4 + hq) ^ (row&7)) << 4)];
  }
  bf16x8 aH[4]; loadA(aH, sh, lane);
  int col0 = lane & 15, hq = lane >> 4;
  for (int n0l=0; n0l<8; n0l++){
    f32x4 accR = {0.f,0.f,0.f,0.f}, accZ = {0.f,0.f,0.f,0.f};
    f32x4 accI = {0.f,0.f,0.f,0.f}, accH = {0.f,0.f,0.f,0.f};
    #pragma unroll
    for (int k0=0;k0<8;k0++)
      accR = __builtin_amdgcn_mfma_f32_16x16x32_bf16(aX[k0], *(const bf16x8*)&Wih[(((n0l   )*8 + k0)*64 + lane)*8], accR, 0,0,0);
    #pragma unroll
    for (int k0=0;k0<4;k0++)
      accR = __builtin_amdgcn_mfma_f32_16x16x32_bf16(aH[k0], *(const bf16x8*)&Whh[(((n0l   )*4 + k0)*64 + lane)*8], accR, 0,0,0);
    #pragma unroll
    for (int k0=0;k0<8;k0++)
      accZ = __builtin_amdgcn_mfma_f32_16x16x32_bf16(aX[k0], *(const bf16x8*)&Wih[(((8+n0l )*8 + k0)*64 + lane)*8], accZ, 0,0,0);
    #pragma unroll
    for (int k0=0;k0<4;k0++)
      accZ = __builtin_amdgcn_mfma_f32_16x16x32_bf16(aH[k0], *(const bf16x8*)&Whh[(((8+n0l )*4 + k0)*64 + lane)*8], accZ, 0,0,0);
    #pragma unroll
    for (int k0=0;k0<8;k0++)
      accI = __builtin_amdgcn_mfma_f32_16x16x32_bf16(aX[k0], *(const bf16x8*)&Wih[(((16+n0l)*8 + k0)*64 + lane)*8], accI, 0,0,0);
    #pragma unroll
    for (int k0=0;k0<4;k0++)
      accH = __builtin_amdgcn_mfma_f32_16x16x32_bf16(aH[k0], *(const bf16x8*)&Whh[(((16+n0l)*4 + k0)*64 + lane)*8], accH, 0,0,0);
    int col = n0l*16 + col0;
    float br  = bih[col] + bhh[col];
    float bz  = bih[DD + col] + bhh[DD + col];
    float bin = bih[2*DD + col], bhn = bhh[2*DD + col];
    #pragma unroll
    for (int r=0;r<4;r++){
      float rr = sigm(accR[r] + br);
      float zz = sigm(accZ[r] + bz);
      float nn = tanhf(accI[r] + bin + rr*(accH[r] + bhn));
      int row = hq*4 + r;
      float hp = b2f(*(const unsigned short*)&sh[row*256 + (((col>>3) ^ (row&7)) << 4) + (col&7)*2]);
      float hv = (1.f - zz)*nn + zz*hp;
      // stash f32 result into sXg region (aX already in regs): [16][128] f32
      *(float*)&sXg[row*512 + (((col>>2) ^ (row&7)) << 4) + (col&3)*4] = hv;
    }
  }
  // cooperative store h rows
  #pragma unroll
  for (int q=0;q<8;q++){
    int i = lane + q*64; int row = i>>5, cb = i&31;
    *(float4*)&h[(size_t)(r0+row)*DD + cb*4] = *(const float4*)&sXg[row*512 + ((cb ^ (row&7)) << 4)];
  }
}

// ---------------- per-graph mean readout ----------------
__global__ __launch_bounds__(256) void k_batchsum(
    const float* __restrict__ v_emb, const int* __restrict__ vb,
    float* __restrict__ g_sum, float* __restrict__ g_cnt)
{
  int c = threadIdx.x & (DD-1);
  int half = threadIdx.x >> 7;
  int rs = blockIdx.x*128 + half*64;
  if (rs >= VN) return;
  int re = rs + 64; if (re > VN) re = VN;
  float acc = 0.f, cnt = 0.f;
  int cur = vb[rs];
  for (int r = rs; r < re; r++){
    int b = vb[r];
    if (b != cur){
      atomicAdd(&g_sum[cur*DD + c], acc);
      if (c == 0) atomicAdd(&g_cnt[cur], cnt);
      acc = 0.f; cnt = 0.f; cur = b;
    }
    acc += v_emb[(size_t)r*DD + c];
    cnt += 1.f;
  }
  atomicAdd(&g_sum[cur*DD + c], acc);
  if (c == 0) atomicAdd(&g_cnt[cur], cnt);
}

__global__ __launch_bounds__(128) void k_readout(
    const float* __restrict__ g_sum, const float* __restrict__ g_cnt,
    const float* __restrict__ W1, const float* __restrict__ b1,
    const float* __restrict__ W2, const float* __restrict__ b2,
    float* __restrict__ out)
{
  __shared__ float sg[DD];
  __shared__ float sr[DD];
  int b = blockIdx.x, c = threadIdx.x;
  float rc = 1.0f / fmaxf(g_cnt[b], 1.0f);
  sg[c] = g_sum[b*DD + c] * rc;
  __syncthreads();
  float a = b1[c];
  for (int k=0;k<DD;k++) a = fmaf(sg[k], W1[(size_t)k*DD + c], a);
  a = fmaxf(a, 0.f);
  sr[c] = a * W2[c];
  __syncthreads();
  for (int s=64; s>0; s>>=1){
    if (c < s) sr[c] += sr[c+s];
    __syncthreads();
  }
  if (c == 0) out[b] = sigm(sr[0] + b2[0]);
}

// ---------------- orchestration ----------------
extern "C" void kernel_launch(void* const* d_in, const int* in_sizes, int n_in,
                              void* d_out, int out_size, void* d_ws, size_t ws_size,
                              hipStream_t stream)
{
  const int* vE = (const int*)d_in[0];
  const int* cE = (const int*)d_in[1];
  const int* pE = (const int*)d_in[2];
  const int* nE = (const int*)d_in[3];
  const int* vb = (const int*)d_in[4];
  const float* v_init = (const float*)d_in[5];
  const float* c_init = (const float*)d_in[6];
  const float* mW1[4]; const float* mb1[4]; const float* mW2[4]; const float* mb2[4];
  for (int m=0;m<4;m++){
    mW1[m] = (const float*)d_in[7 + m*4 + 0];
    mb1[m] = (const float*)d_in[7 + m*4 + 1];
    mW2[m] = (const float*)d_in[7 + m*4 + 2];
    mb2[m] = (const float*)d_in[7 + m*4 + 3];
  }
  const float* gc_Wih = (const float*)d_in[23];
  const float* gc_Whh = (const float*)d_in[24];
  const float* gc_bih = (const float*)d_in[25];
  const float* gc_bhh = (const float*)d_in[26];
  const float* gv_Wih = (const float*)d_in[27];
  const float* gv_Whh = (const float*)d_in[28];
  const float* gv_bih = (const float*)d_in[29];
  const float* gv_bhh = (const float*)d_in[30];
  const float* ro_W1 = (const float*)d_in[31];
  const float* ro_b1 = (const float*)d_in[32];
  const float* ro_W2 = (const float*)d_in[33];
  const float* ro_b2 = (const float*)d_in[34];
  float* out = (float*)d_out;

  char* base = (char*)d_ws;
  size_t off = 0;
  auto alloc = [&](size_t n)->void*{ void* p = base + off; off += (n + 255) & ~(size_t)255; return p; };
  int* cnt4    = (int*)alloc((size_t)SCN*4);
  int* fill4   = (int*)alloc((size_t)SCN*4);
  int* starts  = (int*)alloc(((size_t)SCN+1)*4);
  int* bsum    = (int*)alloc(512*4);
  int* boff    = (int*)alloc(512*4);
  int* p_v     = (int*)alloc((size_t)EPN*4);
  int* p_c     = (int*)alloc((size_t)EPN*4);
  int* n_v     = (int*)alloc((size_t)ENN*4);
  int* n_c     = (int*)alloc((size_t)ENN*4);
  int* listBuf = (int*)alloc((size_t)2*(EPN+ENN)*4);
  float* rdeg4 = (float*)alloc((size_t)SCN*4);
  float* v_emb = (float*)alloc((size_t)VN*DD*4);
  float* c_emb = (float*)alloc((size_t)CN*DD*4);
  unsigned short* Hp = (unsigned short*)alloc((size_t)CN*DD*2);
  unsigned short* Hn = (unsigned short*)alloc((size_t)CN*DD*2);
  unsigned short* Xg = (unsigned short*)alloc((size_t)CN*2*DD*2);
  unsigned short* P_W1[4]; unsigned short* P_W2[4];
  for (int m=0;m<4;m++){
    P_W1[m] = (unsigned short*)alloc((size_t)DD*DD*2);
    P_W2[m] = (unsigned short*)alloc((size_t)DD*DD*2);
  }
  unsigned short* P_gcih = (unsigned short*)alloc((size_t)2*DD*3*DD*2);
  unsigned short* P_gchh = (unsigned short*)alloc((size_t)DD*3*DD*2);
  unsigned short* P_gvih = (unsigned short*)alloc((size_t)2*DD*3*DD*2);
  unsigned short* P_gvhh = (unsigned short*)alloc((size_t)DD*3*DD*2);
  float* g_sum = (float*)alloc((size_t)BN*DD*4);
  float* g_cnt = (float*)alloc((size_t)BN*4);
  (void)ws_size; (void)in_sizes; (void)n_in; (void)out_size;

  hipMemsetAsync(cnt4, 0, (size_t)SCN*4, stream);
  hipMemsetAsync(fill4, 0, (size_t)SCN*4, stream);

  k_edges<<<(EPN+255)/256, 256, 0, stream>>>(vE, cE, pE, nE, p_v, p_c, n_v, n_c, cnt4);
  k_scan1<<<SC_NB, 256, 0, stream>>>(cnt4, starts, bsum);
  k_scan2<<<1, 512, 0, stream>>>(bsum, boff, starts + SCN);
  k_scan3<<<SC_NB, 256, 0, stream>>>(starts, boff);
  k_fill<<<(EPN+255)/256, 256, 0, stream>>>(p_v, p_c, n_v, n_c, starts, fill4, listBuf);
  k_rdeg<<<(SCN+255)/256, 256, 0, stream>>>(cnt4, rdeg4);

  for (int m=0;m<4;m++){
    k_pack<<<(DD*DD+255)/256, 256, 0, stream>>>(mW1[m], P_W1[m], DD, DD);
    k_pack<<<(DD*DD+255)/256, 256, 0, stream>>>(mW2[m], P_W2[m], DD, DD);
  }
  k_pack<<<(2*DD*3*DD+255)/256, 256, 0, stream>>>(gc_Wih, P_gcih, 2*DD, 3*DD);
  k_pack<<<(DD*3*DD+255)/256, 256, 0, stream>>>(gc_Whh, P_gchh, DD, 3*DD);
  k_pack<<<(2*DD*3*DD+255)/256, 256, 0, stream>>>(gv_Wih, P_gvih, 2*DD, 3*DD);
  k_pack<<<(DD*3*DD+255)/256, 256, 0, stream>>>(gv_Whh, P_gvhh, DD, 3*DD);

  k_init<<<((size_t)VN*DD+255)/256, 256, 0, stream>>>(v_init, v_emb, VN*DD);
  k_init<<<((size_t)CN*DD+255)/256, 256, 0, stream>>>(c_init, c_emb, CN*DD);

  int mlpV = (VN+63)/64, mlpC = (CN+63)/64;
  for (int it=0; it<3; ++it){
    // ---- v -> c ----
    k_mlp2dual<<<mlpV, 256, 0, stream>>>(v_emb, P_W1[0], mb1[0], P_W2[0], mb2[0],
                                                  P_W1[1], mb1[1], P_W2[1], mb2[1], Hp, Hn, VN);
    k_aggr<<<CN/4, 256, 0, stream>>>(Hp, Hn, starts, rdeg4, listBuf, Xg, 2*VN, 2*VN+CN, CN);
    k_gru<<<mlpC, 256, 0, stream>>>(c_emb, Xg, P_gcih, P_gchh, gc_bih, gc_bhh, CN);
    // ---- c -> v ----
    k_mlp2dual<<<mlpC, 256, 0, stream>>>(c_emb, P_W1[2], mb1[2], P_W2[2], mb2[2],
                                                  P_W1[3], mb1[3], P_W2[3], mb2[3], Hp, Hn, CN);
    k_aggr<<<VN/4, 256, 0, stream>>>(Hp, Hn, starts, rdeg4, listBuf, Xg, 0, VN, VN);
    k_gru<<<mlpV, 256, 0, stream>>>(v_emb, Xg, P_gvih, P_gvhh, gv_bih, gv_bhh, VN);
  }

  hipMemsetAsync(g_sum, 0, (size_t)BN*DD*4, stream);
  hipMemsetAsync(g_cnt, 0, (size_t)BN*4, stream);
  k_batchsum<<<(VN+127)/128, 256, 0, stream>>>(v_emb, vb, g_sum, g_cnt);
  k_readout<<<BN, 128, 0, stream>>>(g_sum, g_cnt, ro_W1, ro_b1, ro_W2, ro_b2, out);
}